// Round 6
// baseline (651.041 us; speedup 1.0000x reference)
//
#include <hip/hip_runtime.h>
#include <cmath>

typedef __attribute__((ext_vector_type(8))) __bf16 v8bf;
typedef __attribute__((ext_vector_type(4))) float  v4f;

#define DEV static __device__ __forceinline__

DEV unsigned short f2bf(float f) {
  unsigned u = __builtin_bit_cast(unsigned, f);
  unsigned r = u + 0x7fffu + ((u >> 16) & 1u);   // RNE
  return (unsigned short)(r >> 16);
}
DEV float bf2f(unsigned short s) {
  return __builtin_bit_cast(float, ((unsigned)s) << 16);
}
DEV v8bf ld8(const unsigned short* p) { return *(const v8bf*)p; }

// async global->LDS, 16 B per lane; LDS dest = wave-uniform base + lane*16
DEV void gl16(const unsigned short* g, unsigned short* l) {
  __builtin_amdgcn_global_load_lds(
      (const __attribute__((address_space(1))) unsigned int*)g,
      (__attribute__((address_space(3))) unsigned int*)l, 16, 0, 0);
}

// ---------------- fused prep: cvt_x | weight transpose | bias pack ----------------
// grid 8204: [0,4096) cvt_x, [4096,8192) trans (4 matrices x 1024 tiles), [8192,8204) bias
__global__ __launch_bounds__(256) void k_prep(const float* __restrict__ x,
                                              const float* __restrict__ Wq,
                                              const float* __restrict__ Wk,
                                              const float* __restrict__ Wv,
                                              const float* __restrict__ Wo,
                                              const float* __restrict__ bq,
                                              const float* __restrict__ bk,
                                              const float* __restrict__ bv,
                                              unsigned short* __restrict__ xb,
                                              unsigned short* __restrict__ WT,
                                              unsigned short* __restrict__ WoT,
                                              float* __restrict__ bqkv) {
  __shared__ float t[32][33];
  int bx = blockIdx.x, tid = threadIdx.x;
  if (bx < 4096) {                               // x fp32 -> bf16, 4 elems/thread
    int i = bx * 256 + tid;
    float4 v = ((const float4*)x)[i];
    unsigned lo = (unsigned)f2bf(v.x) | ((unsigned)f2bf(v.y) << 16);
    unsigned hi = (unsigned)f2bf(v.z) | ((unsigned)f2bf(v.w) << 16);
    ((uint2*)xb)[i] = make_uint2(lo, hi);
  } else if (bx < 8192) {                        // W[k][n] -> WT[n][k] bf16
    int rem = bx - 4096;
    int z = rem >> 10, r2 = rem & 1023;
    const float* src = (z == 0) ? Wq : (z == 1) ? Wk : (z == 2) ? Wv : Wo;
    unsigned short* dst = (z < 3) ? WT + z * 1048576 : WoT;
    int n0 = (r2 & 31) * 32, k0 = (r2 >> 5) * 32;
    int tx = tid & 31, ty = tid >> 5;
    for (int r = ty; r < 32; r += 8)
      t[r][tx] = src[(k0 + r) * 1024 + n0 + tx];
    __syncthreads();
    for (int r = ty; r < 32; r += 8)
      dst[(n0 + r) * 1024 + k0 + tx] = f2bf(t[tx][r]);
  } else {                                       // bias concat
    int i = (bx - 8192) * 256 + tid;
    float v = (i < 1024) ? bq[i] : (i < 2048 ? bk[i - 1024] : bv[i - 2048]);
    bqkv[i] = v;
  }
}

// ---------------- bf16 MFMA GEMM (m97 structure): QKV proj ----------------
// 128x128 tile, BK=32, global_load_lds width-16 staging, 4 waves each 64x64.
// Q/K block-columns (n0<2048) write QKV rows; V block-columns (n0>=2048) write
// straight into Vtg TRANSPOSED from registers (kills the separate transv pass:
// for fixed lane-m the q4 x packed-r stores cover 32 contiguous bytes per row).
__global__ __launch_bounds__(256) void k_gemm1(const unsigned short* __restrict__ A,
                                               const unsigned short* __restrict__ Bt,
                                               const float* __restrict__ bias,
                                               unsigned short* __restrict__ Cout,
                                               unsigned short* __restrict__ Vtg) {
  constexpr int K = 1024;
  __shared__ __attribute__((aligned(16))) unsigned short As[128 * 32];
  __shared__ __attribute__((aligned(16))) unsigned short Bs[128 * 32];
  int tid = threadIdx.x;
  int wave = tid >> 6, lane = tid & 63;
  int m0 = blockIdx.y * 128, n0 = blockIdx.x * 128;
  int wm = (wave >> 1) * 64, wn = (wave & 1) * 64;
  int m = lane & 15, q4 = lane >> 4;
  int arow = tid >> 2, acol = (tid & 3) * 8;
  v4f acc[4][4] = {};
  const unsigned short* ga0 = A + (m0 + arow) * K + acol;
  const unsigned short* ga1 = A + (m0 + 64 + arow) * K + acol;
  const unsigned short* gb0 = Bt + (n0 + arow) * K + acol;
  const unsigned short* gb1 = Bt + (n0 + 64 + arow) * K + acol;
  unsigned short* lA0 = As + wave * 512;
  unsigned short* lA1 = As + 2048 + wave * 512;
  unsigned short* lB0 = Bs + wave * 512;
  unsigned short* lB1 = Bs + 2048 + wave * 512;

  for (int kt = 0; kt < K; kt += 32) {
    gl16(ga0 + kt, lA0);
    gl16(ga1 + kt, lA1);
    gl16(gb0 + kt, lB0);
    gl16(gb1 + kt, lB1);
    __syncthreads();
    v8bf af[4], bfv[4];
#pragma unroll
    for (int mt = 0; mt < 4; mt++) af[mt] = ld8(&As[(wm + mt * 16 + m) * 32 + q4 * 8]);
#pragma unroll
    for (int nt = 0; nt < 4; nt++) bfv[nt] = ld8(&Bs[(wn + nt * 16 + m) * 32 + q4 * 8]);
#pragma unroll
    for (int mt = 0; mt < 4; mt++)
#pragma unroll
      for (int nt = 0; nt < 4; nt++)
        acc[mt][nt] = __builtin_amdgcn_mfma_f32_16x16x32_bf16(af[mt], bfv[nt], acc[mt][nt], 0, 0, 0);
    __syncthreads();
  }
  if (n0 < 2048) {
    // Q/K: normal row-major store into QKV
#pragma unroll
    for (int mt = 0; mt < 4; mt++)
#pragma unroll
      for (int nt = 0; nt < 4; nt++) {
        int col = n0 + wn + nt * 16 + m;
        float bb = bias[col];
#pragma unroll
        for (int r = 0; r < 4; r++) {
          int row = m0 + wm + mt * 16 + q4 * 4 + r;
          Cout[row * 3072 + col] = f2bf(acc[mt][nt][r] + bb);
        }
      }
  } else {
    // V: write transposed into Vtg[(b*16+h)*64+d][s], packed 4 bf16 (8 B) per store
    int b = m0 >> 11;                            // block-uniform (128 | 2048)
#pragma unroll
    for (int mt = 0; mt < 4; mt++)
#pragma unroll
      for (int nt = 0; nt < 4; nt++) {
        int col = n0 + wn + nt * 16 + m;         // 2048 + h*64 + d
        float bb = bias[col];
        int dfull = col - 2048;
        int s = (m0 & 2047) + wm + mt * 16 + q4 * 4;   // r=0 element
        unsigned short e0 = f2bf(acc[mt][nt][0] + bb);
        unsigned short e1 = f2bf(acc[mt][nt][1] + bb);
        unsigned short e2 = f2bf(acc[mt][nt][2] + bb);
        unsigned short e3 = f2bf(acc[mt][nt][3] + bb);
        uint2 pk = make_uint2((unsigned)e0 | ((unsigned)e1 << 16),
                              (unsigned)e2 | ((unsigned)e3 << 16));
        *(uint2*)&Vtg[((size_t)(b * 1024 + dfull)) * 2048 + s] = pk;
      }
  }
}

// ---------------- sliding-window attention (band only) ----------------
// One block = (b, h, 64 queries), 4 waves x 16 q. Writes Oatt bf16 and band cb bf16.
__global__ __launch_bounds__(256) void k_attn(const unsigned short* __restrict__ QKV,
                                              const unsigned short* __restrict__ Vtg,
                                              unsigned short* __restrict__ Oatt,
                                              unsigned short* __restrict__ cb) {
  constexpr int VTS = 208;
  constexpr int PSS = 168;
  __shared__ __attribute__((aligned(16))) unsigned short Vt[64 * VTS];
  __shared__ __attribute__((aligned(16))) unsigned short Ps[4][16 * PSS];
  int b = blockIdx.z, h = blockIdx.y, i0 = blockIdx.x * 64;
  int tid = threadIdx.x, wave = tid >> 6, lane = tid & 63;
  int kbase = i0 - 128;
  const int ld = 3072;
  const unsigned short* Qg = QKV + b * 2048 * ld + h * 64;
  const unsigned short* Kg = Qg + 1024;

  // stage V from pre-transposed Vtg: 64 d-rows x 192 keys, b128 both sides
  const unsigned short* vsrc = Vtg + (size_t)(b * 16 + h) * 64 * 2048;
  for (int idx = tid; idx < 1536; idx += 256) {
    int row = idx / 24, c16 = idx % 24;
    int gcol = kbase + c16 * 8;
    if (gcol < 0) gcol = 0;                       // clamp; P mask zeroes these keys
    v8bf vv = ld8(vsrc + (size_t)row * 2048 + gcol);
    *(v8bf*)&Vt[row * VTS + c16 * 8] = vv;
  }
  // zero Vt cols [192,208): wave3's PV c=4 chunk reads them
  {
    int row = tid >> 2, c4 = (tid & 3) * 4;
    *(uint2*)&Vt[row * VTS + 192 + c4] = make_uint2(0u, 0u);
  }
  // zero Ps pad cols [144,168)
  for (int c = lane; c < 16 * 24; c += 64)
    Ps[wave][(c / 24) * PSS + 144 + (c % 24)] = 0;
  __syncthreads();

  int qb = i0 + wave * 16;
  int m = lane & 15, q4 = lane >> 4;

  const unsigned short* qrow = Qg + (qb + m) * ld;
  v8bf qa0 = ld8(qrow + q4 * 8);
  v8bf qa1 = ld8(qrow + 32 + q4 * 8);

  v4f sc[9];
#pragma unroll
  for (int n = 0; n < 9; n++) {
    int key = kbase + wave * 16 + n * 16 + m;
    int kg = key < 0 ? 0 : key;
    const unsigned short* krow = Kg + kg * ld;
    v8bf kb0 = ld8(krow + q4 * 8);
    v8bf kb1 = ld8(krow + 32 + q4 * 8);
    v4f z = {0.f, 0.f, 0.f, 0.f};
    z = __builtin_amdgcn_mfma_f32_16x16x32_bf16(qa0, kb0, z, 0, 0, 0);
    z = __builtin_amdgcn_mfma_f32_16x16x32_bf16(qa1, kb1, z, 0, 0, 0);
    sc[n] = z;
  }
  float mx[4] = {-3e38f, -3e38f, -3e38f, -3e38f};
#pragma unroll
  for (int n = 0; n < 9; n++)
#pragma unroll
    for (int r = 0; r < 4; r++) {
      int i = qb + q4 * 4 + r;
      int j = kbase + wave * 16 + n * 16 + m;
      float v = sc[n][r] * 0.125f;
      bool ok = (j >= 0) && (j <= i) && (j > i - 128);
      v = ok ? v : -3e38f;
      sc[n][r] = v;
      mx[r] = fmaxf(mx[r], v);
    }
#pragma unroll
  for (int o = 1; o < 16; o <<= 1)
#pragma unroll
    for (int r = 0; r < 4; r++) mx[r] = fmaxf(mx[r], __shfl_xor(mx[r], o, 64));
  float sum[4] = {0.f, 0.f, 0.f, 0.f};
#pragma unroll
  for (int n = 0; n < 9; n++)
#pragma unroll
    for (int r = 0; r < 4; r++) {
      float p = __expf(sc[n][r] - mx[r]);
      sc[n][r] = p;
      sum[r] += p;
    }
#pragma unroll
  for (int o = 1; o < 16; o <<= 1)
#pragma unroll
    for (int r = 0; r < 4; r++) sum[r] += __shfl_xor(sum[r], o, 64);
  float inv[4];
#pragma unroll
  for (int r = 0; r < 4; r++) inv[r] = 1.0f / sum[r];

#pragma unroll
  for (int n = 0; n < 9; n++)
#pragma unroll
    for (int r = 0; r < 4; r++)
      Ps[wave][(q4 * 4 + r) * PSS + n * 16 + m] = f2bf(sc[n][r] * inv[r]);
  __syncthreads();

  v4f oacc[4] = {};
#pragma unroll
  for (int c = 0; c < 5; c++) {
    v8bf pa = ld8(&Ps[wave][m * PSS + c * 32 + q4 * 8]);
#pragma unroll
    for (int dt = 0; dt < 4; dt++) {
      v8bf vb = ld8(&Vt[(dt * 16 + m) * VTS + wave * 16 + c * 32 + q4 * 8]);
      oacc[dt] = __builtin_amdgcn_mfma_f32_16x16x32_bf16(pa, vb, oacc[dt], 0, 0, 0);
    }
  }
#pragma unroll
  for (int dt = 0; dt < 4; dt++)
#pragma unroll
    for (int r = 0; r < 4; r++)
      Oatt[(b * 2048 + qb + q4 * 4 + r) * 1024 + h * 64 + dt * 16 + m] = f2bf(oacc[dt][r]);

  for (int R = 0; R < 16; R++) {
    int row = (b * 16 + h) * 2048 + qb + R;
    unsigned short p0 = Ps[wave][R * PSS + R + 1 + lane * 2];
    unsigned short p1 = Ps[wave][R * PSS + R + 2 + lane * 2];
    ((unsigned*)cb)[row * 64 + lane] = (unsigned)p0 | ((unsigned)p1 << 16);
  }
}

// ---------------- fused tail: out-proj GEMM (blocks 0..255) + dense-weights writer ----------------
// Both depend only on k_attn; gemm blocks first so MFMA work hides under the 537 MB write.
__global__ __launch_bounds__(256) void k_tail(const unsigned short* __restrict__ Oat,
                                              const unsigned short* __restrict__ WoT,
                                              const float* __restrict__ bo,
                                              float* __restrict__ out,
                                              const unsigned short* __restrict__ cb,
                                              float* __restrict__ wout) {
  __shared__ __attribute__((aligned(16))) unsigned short As[128 * 32];
  __shared__ __attribute__((aligned(16))) unsigned short Bs[128 * 32];
  int tid = threadIdx.x, wave = tid >> 6, lane = tid & 63;

  if (blockIdx.x < 256) {
    // ---- gemm role: out[4096][1024] = Oat[4096][1024] x WoT^T + bo
    constexpr int K = 1024;
    int bx = blockIdx.x;
    int n0 = (bx & 7) * 128, m0 = (bx >> 3) * 128;
    int wm = (wave >> 1) * 64, wn = (wave & 1) * 64;
    int m = lane & 15, q4 = lane >> 4;
    int arow = tid >> 2, acol = (tid & 3) * 8;
    v4f acc[4][4] = {};
    const unsigned short* ga0 = Oat + (m0 + arow) * K + acol;
    const unsigned short* ga1 = Oat + (m0 + 64 + arow) * K + acol;
    const unsigned short* gb0 = WoT + (n0 + arow) * K + acol;
    const unsigned short* gb1 = WoT + (n0 + 64 + arow) * K + acol;
    unsigned short* lA0 = As + wave * 512;
    unsigned short* lA1 = As + 2048 + wave * 512;
    unsigned short* lB0 = Bs + wave * 512;
    unsigned short* lB1 = Bs + 2048 + wave * 512;
    for (int kt = 0; kt < K; kt += 32) {
      gl16(ga0 + kt, lA0);
      gl16(ga1 + kt, lA1);
      gl16(gb0 + kt, lB0);
      gl16(gb1 + kt, lB1);
      __syncthreads();
      v8bf af[4], bfv[4];
#pragma unroll
      for (int mt = 0; mt < 4; mt++) af[mt] = ld8(&As[(wm + mt * 16 + m) * 32 + q4 * 8]);
#pragma unroll
      for (int nt = 0; nt < 4; nt++) bfv[nt] = ld8(&Bs[(wn + nt * 16 + m) * 32 + q4 * 8]);
#pragma unroll
      for (int mt = 0; mt < 4; mt++)
#pragma unroll
        for (int nt = 0; nt < 4; nt++)
          acc[mt][nt] = __builtin_amdgcn_mfma_f32_16x16x32_bf16(af[mt], bfv[nt], acc[mt][nt], 0, 0, 0);
      __syncthreads();
    }
#pragma unroll
    for (int mt = 0; mt < 4; mt++)
#pragma unroll
      for (int nt = 0; nt < 4; nt++) {
        int col = n0 + wn + nt * 16 + m;
        float bb = bo[col];
#pragma unroll
        for (int r = 0; r < 4; r++) {
          int row = m0 + wm + mt * 16 + q4 * 4 + r;
          out[row * 1024 + col] = acc[mt][nt][r] + bb;
        }
      }
  } else {
    // ---- writer role: dense weights rows, nontemporal streaming stores
    int wb = blockIdx.x - 256;
    int rbase = wb * 16 + wave * 4;
    for (int rr = 0; rr < 4; rr++) {
      int row = rbase + rr;
      int i = row & 2047;
      float* rowp = wout + (size_t)row * 2048;
      const unsigned short* crow = cb + (size_t)row * 128;
      int lo = i - 127;
#pragma unroll
      for (int it = 0; it < 8; it++) {
        int col = it * 256 + lane * 4;
        v4f v = {0.f, 0.f, 0.f, 0.f};
        if (col <= i && col + 3 >= lo) {
#pragma unroll
          for (int e = 0; e < 4; e++) {
            int j = col + e;
            if (j >= lo && j <= i && j >= 0)
              v[e] = bf2f(crow[j - lo]);
          }
        }
        __builtin_nontemporal_store(v, (v4f*)(rowp + col));
      }
    }
  }
}

// ---------------- host launch ----------------
extern "C" void kernel_launch(void* const* d_in, const int* in_sizes, int n_in,
                              void* d_out, int out_size, void* d_ws, size_t ws_size,
                              hipStream_t stream) {
  (void)in_sizes; (void)n_in; (void)out_size; (void)ws_size;
  const float* x  = (const float*)d_in[0];
  const float* Wq = (const float*)d_in[1];
  const float* bq = (const float*)d_in[2];
  const float* Wk = (const float*)d_in[3];
  const float* bk = (const float*)d_in[4];
  const float* Wv = (const float*)d_in[5];
  const float* bv = (const float*)d_in[6];
  const float* Wo = (const float*)d_in[7];
  const float* bo = (const float*)d_in[8];

  char* ws = (char*)d_ws;
  unsigned short* xb   = (unsigned short*)(ws);                  //  8,388,608 B
  unsigned short* WT   = (unsigned short*)(ws + 8388608);        //  6,291,456 B  [3072][1024]
  unsigned short* WoT  = (unsigned short*)(ws + 14680064);       //  2,097,152 B  [1024][1024]
  float*          bqkv = (float*)(ws + 16777216);                //     12,288 B
  unsigned short* QKV  = (unsigned short*)(ws + 16789504);       // 25,165,824 B  [4096][3072] (V third unused)
  unsigned short* Oat  = (unsigned short*)(ws + 41955328);       //  8,388,608 B  [4096][1024]
  unsigned short* cb   = (unsigned short*)(ws + 50343936);       // 16,777,216 B  [65536][128]
  unsigned short* Vtg  = (unsigned short*)(ws + 67121152);       //  8,388,608 B  [2048][2048]

  float* out  = (float*)d_out;          // [2,2048,1024]
  float* wout = out + 4194304;          // [2,16,2048,2048]

  k_prep<<<8204, 256, 0, stream>>>(x, Wq, Wk, Wv, Wo, bq, bk, bv, xb, WT, WoT, bqkv);
  k_gemm1<<<dim3(24, 32), 256, 0, stream>>>(xb, WT, bqkv, QKV, Vtg);
  k_attn<<<dim3(32, 16, 2), 256, 0, stream>>>(QKV, Vtg, Oat, cb);
  k_tail<<<4352, 256, 0, stream>>>(Oat, WoT, bo, out, cb, wout);
}

// Round 7
// 650.171 us; speedup vs baseline: 1.0013x; 1.0013x over previous
//
#include <hip/hip_runtime.h>
#include <cmath>

typedef __attribute__((ext_vector_type(8))) __bf16 v8bf;
typedef __attribute__((ext_vector_type(4))) float  v4f;

#define DEV static __device__ __forceinline__

DEV unsigned short f2bf(float f) {
  unsigned u = __builtin_bit_cast(unsigned, f);
  unsigned r = u + 0x7fffu + ((u >> 16) & 1u);   // RNE
  return (unsigned short)(r >> 16);
}
DEV float bf2f(unsigned short s) {
  return __builtin_bit_cast(float, ((unsigned)s) << 16);
}
DEV v8bf ld8(const unsigned short* p) { return *(const v8bf*)p; }

// async global->LDS, 16 B per lane; LDS dest = wave-uniform base + lane*16
DEV void gl16(const unsigned short* g, unsigned short* l) {
  __builtin_amdgcn_global_load_lds(
      (const __attribute__((address_space(1))) unsigned int*)g,
      (__attribute__((address_space(3))) unsigned int*)l, 16, 0, 0);
}

// ---------------- fused prep: cvt_x | weight transpose | bias pack ----------------
__global__ __launch_bounds__(256) void k_prep(const float* __restrict__ x,
                                              const float* __restrict__ Wq,
                                              const float* __restrict__ Wk,
                                              const float* __restrict__ Wv,
                                              const float* __restrict__ Wo,
                                              const float* __restrict__ bq,
                                              const float* __restrict__ bk,
                                              const float* __restrict__ bv,
                                              unsigned short* __restrict__ xb,
                                              unsigned short* __restrict__ WT,
                                              unsigned short* __restrict__ WoT,
                                              float* __restrict__ bqkv) {
  __shared__ float t[32][33];
  int bx = blockIdx.x, tid = threadIdx.x;
  if (bx < 4096) {                               // x fp32 -> bf16, 4 elems/thread
    int i = bx * 256 + tid;
    float4 v = ((const float4*)x)[i];
    unsigned lo = (unsigned)f2bf(v.x) | ((unsigned)f2bf(v.y) << 16);
    unsigned hi = (unsigned)f2bf(v.z) | ((unsigned)f2bf(v.w) << 16);
    ((uint2*)xb)[i] = make_uint2(lo, hi);
  } else if (bx < 8192) {                        // W[k][n] -> WT[n][k] bf16
    int rem = bx - 4096;
    int z = rem >> 10, r2 = rem & 1023;
    const float* src = (z == 0) ? Wq : (z == 1) ? Wk : (z == 2) ? Wv : Wo;
    unsigned short* dst = (z < 3) ? WT + z * 1048576 : WoT;
    int n0 = (r2 & 31) * 32, k0 = (r2 >> 5) * 32;
    int tx = tid & 31, ty = tid >> 5;
    for (int r = ty; r < 32; r += 8)
      t[r][tx] = src[(k0 + r) * 1024 + n0 + tx];
    __syncthreads();
    for (int r = ty; r < 32; r += 8)
      dst[(n0 + r) * 1024 + k0 + tx] = f2bf(t[tx][r]);
  } else {                                       // bias concat
    int i = (bx - 8192) * 256 + tid;
    float v = (i < 1024) ? bq[i] : (i < 2048 ? bk[i - 1024] : bv[i - 2048]);
    bqkv[i] = v;
  }
}

// ---------------- bf16 MFMA GEMM (m97 structure): QKV proj ----------------
// Q/K block-columns write QKV rows; V block-columns write transposed into Vtg.
__global__ __launch_bounds__(256) void k_gemm1(const unsigned short* __restrict__ A,
                                               const unsigned short* __restrict__ Bt,
                                               const float* __restrict__ bias,
                                               unsigned short* __restrict__ Cout,
                                               unsigned short* __restrict__ Vtg) {
  constexpr int K = 1024;
  __shared__ __attribute__((aligned(16))) unsigned short As[128 * 32];
  __shared__ __attribute__((aligned(16))) unsigned short Bs[128 * 32];
  int tid = threadIdx.x;
  int wave = tid >> 6, lane = tid & 63;
  int m0 = blockIdx.y * 128, n0 = blockIdx.x * 128;
  int wm = (wave >> 1) * 64, wn = (wave & 1) * 64;
  int m = lane & 15, q4 = lane >> 4;
  int arow = tid >> 2, acol = (tid & 3) * 8;
  v4f acc[4][4] = {};
  const unsigned short* ga0 = A + (m0 + arow) * K + acol;
  const unsigned short* ga1 = A + (m0 + 64 + arow) * K + acol;
  const unsigned short* gb0 = Bt + (n0 + arow) * K + acol;
  const unsigned short* gb1 = Bt + (n0 + 64 + arow) * K + acol;
  unsigned short* lA0 = As + wave * 512;
  unsigned short* lA1 = As + 2048 + wave * 512;
  unsigned short* lB0 = Bs + wave * 512;
  unsigned short* lB1 = Bs + 2048 + wave * 512;

  for (int kt = 0; kt < K; kt += 32) {
    gl16(ga0 + kt, lA0);
    gl16(ga1 + kt, lA1);
    gl16(gb0 + kt, lB0);
    gl16(gb1 + kt, lB1);
    __syncthreads();
    v8bf af[4], bfv[4];
#pragma unroll
    for (int mt = 0; mt < 4; mt++) af[mt] = ld8(&As[(wm + mt * 16 + m) * 32 + q4 * 8]);
#pragma unroll
    for (int nt = 0; nt < 4; nt++) bfv[nt] = ld8(&Bs[(wn + nt * 16 + m) * 32 + q4 * 8]);
#pragma unroll
    for (int mt = 0; mt < 4; mt++)
#pragma unroll
      for (int nt = 0; nt < 4; nt++)
        acc[mt][nt] = __builtin_amdgcn_mfma_f32_16x16x32_bf16(af[mt], bfv[nt], acc[mt][nt], 0, 0, 0);
    __syncthreads();
  }
  if (n0 < 2048) {
    // Q/K: normal row-major store into QKV
#pragma unroll
    for (int mt = 0; mt < 4; mt++)
#pragma unroll
      for (int nt = 0; nt < 4; nt++) {
        int col = n0 + wn + nt * 16 + m;
        float bb = bias[col];
#pragma unroll
        for (int r = 0; r < 4; r++) {
          int row = m0 + wm + mt * 16 + q4 * 4 + r;
          Cout[row * 3072 + col] = f2bf(acc[mt][nt][r] + bb);
        }
      }
  } else {
    // V: write transposed into Vtg[(b*16+h)*64+d][s], packed 4 bf16 (8 B) per store
    int b = m0 >> 11;                            // block-uniform
#pragma unroll
    for (int mt = 0; mt < 4; mt++)
#pragma unroll
      for (int nt = 0; nt < 4; nt++) {
        int col = n0 + wn + nt * 16 + m;         // 2048 + h*64 + d
        float bb = bias[col];
        int dfull = col - 2048;
        int s = (m0 & 2047) + wm + mt * 16 + q4 * 4;
        unsigned short e0 = f2bf(acc[mt][nt][0] + bb);
        unsigned short e1 = f2bf(acc[mt][nt][1] + bb);
        unsigned short e2 = f2bf(acc[mt][nt][2] + bb);
        unsigned short e3 = f2bf(acc[mt][nt][3] + bb);
        uint2 pk = make_uint2((unsigned)e0 | ((unsigned)e1 << 16),
                              (unsigned)e2 | ((unsigned)e3 << 16));
        *(uint2*)&Vtg[((size_t)(b * 1024 + dfull)) * 2048 + s] = pk;
      }
  }
}

// ---------------- sliding-window attention: barrier-free, wave-independent ----------------
// One block = (b, h, 64 queries), 4 waves x 16 q. Ps is WAVE-PRIVATE (no barriers);
// V fragments read directly from pre-transposed Vtg (L2-hot) -> LDS 21.5 KB, 4+ blocks/CU.
__global__ __launch_bounds__(256, 4) void k_attn(const unsigned short* __restrict__ QKV,
                                                 const unsigned short* __restrict__ Vtg,
                                                 unsigned short* __restrict__ Oatt,
                                                 unsigned short* __restrict__ cb) {
  constexpr int PSS = 168;
  __shared__ __attribute__((aligned(16))) unsigned short Ps[4][16 * PSS];    // 21.5 KB
  int b = blockIdx.z, h = blockIdx.y, i0 = blockIdx.x * 64;
  int tid = threadIdx.x, wave = tid >> 6, lane = tid & 63;
  int kbase = i0 - 128;
  const int ld = 3072;
  const unsigned short* Qg = QKV + b * 2048 * ld + h * 64;
  const unsigned short* Kg = Qg + 1024;
  const unsigned short* vsrc = Vtg + (size_t)(b * 16 + h) * 64 * 2048;

  // zero Ps pad cols [144,168) so padded PV chunks contribute 0 (wave-local)
  for (int c = lane; c < 16 * 24; c += 64)
    Ps[wave][(c / 24) * PSS + 144 + (c % 24)] = 0;

  int qb = i0 + wave * 16;
  int m = lane & 15, q4 = lane >> 4;

  const unsigned short* qrow = Qg + (qb + m) * ld;
  v8bf qa0 = ld8(qrow + q4 * 8);
  v8bf qa1 = ld8(qrow + 32 + q4 * 8);

  v4f sc[9];
#pragma unroll
  for (int n = 0; n < 9; n++) {
    int key = kbase + wave * 16 + n * 16 + m;
    int kg = key < 0 ? 0 : key;
    const unsigned short* krow = Kg + kg * ld;
    v8bf kb0 = ld8(krow + q4 * 8);
    v8bf kb1 = ld8(krow + 32 + q4 * 8);
    v4f z = {0.f, 0.f, 0.f, 0.f};
    z = __builtin_amdgcn_mfma_f32_16x16x32_bf16(qa0, kb0, z, 0, 0, 0);
    z = __builtin_amdgcn_mfma_f32_16x16x32_bf16(qa1, kb1, z, 0, 0, 0);
    sc[n] = z;
  }
  float mx[4] = {-3e38f, -3e38f, -3e38f, -3e38f};
#pragma unroll
  for (int n = 0; n < 9; n++)
#pragma unroll
    for (int r = 0; r < 4; r++) {
      int i = qb + q4 * 4 + r;
      int j = kbase + wave * 16 + n * 16 + m;
      float v = sc[n][r] * 0.125f;
      bool ok = (j >= 0) && (j <= i) && (j > i - 128);
      v = ok ? v : -3e38f;
      sc[n][r] = v;
      mx[r] = fmaxf(mx[r], v);
    }
#pragma unroll
  for (int o = 1; o < 16; o <<= 1)
#pragma unroll
    for (int r = 0; r < 4; r++) mx[r] = fmaxf(mx[r], __shfl_xor(mx[r], o, 64));
  float sum[4] = {0.f, 0.f, 0.f, 0.f};
#pragma unroll
  for (int n = 0; n < 9; n++)
#pragma unroll
    for (int r = 0; r < 4; r++) {
      float p = __expf(sc[n][r] - mx[r]);
      sc[n][r] = p;
      sum[r] += p;
    }
#pragma unroll
  for (int o = 1; o < 16; o <<= 1)
#pragma unroll
    for (int r = 0; r < 4; r++) sum[r] += __shfl_xor(sum[r], o, 64);
  float inv[4];
#pragma unroll
  for (int r = 0; r < 4; r++) inv[r] = 1.0f / sum[r];

  // P -> wave-private LDS (A-operand layout for PV); compiler inserts lgkmcnt waits
#pragma unroll
  for (int n = 0; n < 9; n++)
#pragma unroll
    for (int r = 0; r < 4; r++)
      Ps[wave][(q4 * 4 + r) * PSS + n * 16 + m] = f2bf(sc[n][r] * inv[r]);

  // PV: out[16 q][64 d]; V B-fragments straight from global Vtg (clamped cols have P=0)
  v4f oacc[4] = {};
#pragma unroll
  for (int c = 0; c < 5; c++) {
    v8bf pa = ld8(&Ps[wave][m * PSS + c * 32 + q4 * 8]);
    int vcol = kbase + wave * 16 + c * 32 + q4 * 8;
    vcol = vcol < 0 ? 0 : (vcol > 2040 ? 2040 : vcol);
#pragma unroll
    for (int dt = 0; dt < 4; dt++) {
      v8bf vb = ld8(vsrc + (size_t)(dt * 16 + m) * 2048 + vcol);
      oacc[dt] = __builtin_amdgcn_mfma_f32_16x16x32_bf16(pa, vb, oacc[dt], 0, 0, 0);
    }
  }
#pragma unroll
  for (int dt = 0; dt < 4; dt++)
#pragma unroll
    for (int r = 0; r < 4; r++)
      Oatt[(b * 2048 + qb + q4 * 4 + r) * 1024 + h * 64 + dt * 16 + m] = f2bf(oacc[dt][r]);

  for (int R = 0; R < 16; R++) {
    int row = (b * 16 + h) * 2048 + qb + R;
    unsigned short p0 = Ps[wave][R * PSS + R + 1 + lane * 2];
    unsigned short p1 = Ps[wave][R * PSS + R + 2 + lane * 2];
    ((unsigned*)cb)[row * 64 + lane] = (unsigned)p0 | ((unsigned)p1 << 16);
  }
}

// ---------------- fused tail: out-proj GEMM (blocks 0..255) + dense-weights writer ----------------
__global__ __launch_bounds__(256) void k_tail(const unsigned short* __restrict__ Oat,
                                              const unsigned short* __restrict__ WoT,
                                              const float* __restrict__ bo,
                                              float* __restrict__ out,
                                              const unsigned short* __restrict__ cb,
                                              float* __restrict__ wout) {
  __shared__ __attribute__((aligned(16))) unsigned short As[128 * 32];
  __shared__ __attribute__((aligned(16))) unsigned short Bs[128 * 32];
  int tid = threadIdx.x, wave = tid >> 6, lane = tid & 63;

  if (blockIdx.x < 256) {
    constexpr int K = 1024;
    int bx = blockIdx.x;
    int n0 = (bx & 7) * 128, m0 = (bx >> 3) * 128;
    int wm = (wave >> 1) * 64, wn = (wave & 1) * 64;
    int m = lane & 15, q4 = lane >> 4;
    int arow = tid >> 2, acol = (tid & 3) * 8;
    v4f acc[4][4] = {};
    const unsigned short* ga0 = Oat + (m0 + arow) * K + acol;
    const unsigned short* ga1 = Oat + (m0 + 64 + arow) * K + acol;
    const unsigned short* gb0 = WoT + (n0 + arow) * K + acol;
    const unsigned short* gb1 = WoT + (n0 + 64 + arow) * K + acol;
    unsigned short* lA0 = As + wave * 512;
    unsigned short* lA1 = As + 2048 + wave * 512;
    unsigned short* lB0 = Bs + wave * 512;
    unsigned short* lB1 = Bs + 2048 + wave * 512;
    for (int kt = 0; kt < K; kt += 32) {
      gl16(ga0 + kt, lA0);
      gl16(ga1 + kt, lA1);
      gl16(gb0 + kt, lB0);
      gl16(gb1 + kt, lB1);
      __syncthreads();
      v8bf af[4], bfv[4];
#pragma unroll
      for (int mt = 0; mt < 4; mt++) af[mt] = ld8(&As[(wm + mt * 16 + m) * 32 + q4 * 8]);
#pragma unroll
      for (int nt = 0; nt < 4; nt++) bfv[nt] = ld8(&Bs[(wn + nt * 16 + m) * 32 + q4 * 8]);
#pragma unroll
      for (int mt = 0; mt < 4; mt++)
#pragma unroll
        for (int nt = 0; nt < 4; nt++)
          acc[mt][nt] = __builtin_amdgcn_mfma_f32_16x16x32_bf16(af[mt], bfv[nt], acc[mt][nt], 0, 0, 0);
      __syncthreads();
    }
#pragma unroll
    for (int mt = 0; mt < 4; mt++)
#pragma unroll
      for (int nt = 0; nt < 4; nt++) {
        int col = n0 + wn + nt * 16 + m;
        float bb = bo[col];
#pragma unroll
        for (int r = 0; r < 4; r++) {
          int row = m0 + wm + mt * 16 + q4 * 4 + r;
          out[row * 1024 + col] = acc[mt][nt][r] + bb;
        }
      }
  } else {
    int wb = blockIdx.x - 256;
    int rbase = wb * 16 + wave * 4;
    for (int rr = 0; rr < 4; rr++) {
      int row = rbase + rr;
      int i = row & 2047;
      float* rowp = wout + (size_t)row * 2048;
      const unsigned short* crow = cb + (size_t)row * 128;
      int lo = i - 127;
#pragma unroll
      for (int it = 0; it < 8; it++) {
        int col = it * 256 + lane * 4;
        v4f v = {0.f, 0.f, 0.f, 0.f};
        if (col <= i && col + 3 >= lo) {
#pragma unroll
          for (int e = 0; e < 4; e++) {
            int j = col + e;
            if (j >= lo && j <= i && j >= 0)
              v[e] = bf2f(crow[j - lo]);
          }
        }
        __builtin_nontemporal_store(v, (v4f*)(rowp + col));
      }
    }
  }
}

// ---------------- host launch ----------------
extern "C" void kernel_launch(void* const* d_in, const int* in_sizes, int n_in,
                              void* d_out, int out_size, void* d_ws, size_t ws_size,
                              hipStream_t stream) {
  (void)in_sizes; (void)n_in; (void)out_size; (void)ws_size;
  const float* x  = (const float*)d_in[0];
  const float* Wq = (const float*)d_in[1];
  const float* bq = (const float*)d_in[2];
  const float* Wk = (const float*)d_in[3];
  const float* bk = (const float*)d_in[4];
  const float* Wv = (const float*)d_in[5];
  const float* bv = (const float*)d_in[6];
  const float* Wo = (const float*)d_in[7];
  const float* bo = (const float*)d_in[8];

  char* ws = (char*)d_ws;
  unsigned short* xb   = (unsigned short*)(ws);                  //  8,388,608 B
  unsigned short* WT   = (unsigned short*)(ws + 8388608);        //  6,291,456 B  [3072][1024]
  unsigned short* WoT  = (unsigned short*)(ws + 14680064);       //  2,097,152 B  [1024][1024]
  float*          bqkv = (float*)(ws + 16777216);                //     12,288 B
  unsigned short* QKV  = (unsigned short*)(ws + 16789504);       // 25,165,824 B  [4096][3072] (V third unused)
  unsigned short* Oat  = (unsigned short*)(ws + 41955328);       //  8,388,608 B  [4096][1024]
  unsigned short* cb   = (unsigned short*)(ws + 50343936);       // 16,777,216 B  [65536][128]
  unsigned short* Vtg  = (unsigned short*)(ws + 67121152);       //  8,388,608 B  [2048][2048]

  float* out  = (float*)d_out;          // [2,2048,1024]
  float* wout = out + 4194304;          // [2,16,2048,2048]

  k_prep<<<8204, 256, 0, stream>>>(x, Wq, Wk, Wv, Wo, bq, bk, bv, xb, WT, WoT, bqkv);
  k_gemm1<<<dim3(24, 32), 256, 0, stream>>>(xb, WT, bqkv, QKV, Vtg);
  k_attn<<<dim3(32, 16, 2), 256, 0, stream>>>(QKV, Vtg, Oat, cb);
  k_tail<<<4352, 256, 0, stream>>>(Oat, WoT, bo, out, cb, wout);
}